// Round 2
// baseline (966.171 us; speedup 1.0000x reference)
//
#include <hip/hip_runtime.h>
#include <hip/hip_bf16.h>

#define N_NODES 8192
#define IN_FEAT 256
#define OUT_F   64
#define NHEAD   4
#define HF      256     // NHEAD*OUT_F
#define NEG     0.2f

typedef unsigned short u16;

__device__ __forceinline__ float bf2f(u16 x) {
    union { unsigned int u; float f; } v; v.u = ((unsigned int)x) << 16; return v.f;
}
__device__ __forceinline__ u16 f2bf(float f) {
    union { unsigned int u; float f; } v; v.f = f;
    unsigned int r = v.u + 0x7FFFu + ((v.u >> 16) & 1u);  // RNE
    return (u16)(r >> 16);
}
__device__ __forceinline__ float leaky(float x) {
    return fmaxf(x, 0.f) + NEG * fminf(x, 0.f);
}

// ---------------------------------------------------------------------------
// K1: per 4 rows: support = X@W (bf16 to ws), f1/f2 head dots,
//     proj = X@Pw^T + proj_b + bias  -> written straight into d_out (fp32).
// ---------------------------------------------------------------------------
#define RPB 4
__global__ __launch_bounds__(256) void k_gemm(
    const float* __restrict__ inp,   // [N, 256]
    const float* __restrict__ W,     // [256, 256] (k-major rows)
    const float* __restrict__ U,     // [H*64] flat
    const float* __restrict__ V,     // [H*64] flat
    const float* __restrict__ Bias,  // [256]
    const float* __restrict__ PW,    // [256 out][256 in]
    const float* __restrict__ PB,    // [256]
    u16*   __restrict__ supp,        // [H][N][64] bf16
    float* __restrict__ f1,          // [H][N]
    float* __restrict__ f2,          // [H][N]
    float* __restrict__ outp)        // [N][256]  proj + bias + proj_b
{
    __shared__ __align__(16) float in_lds[RPB][IN_FEAT];
    const int c  = threadIdx.x;            // output column 0..255
    const int n0 = blockIdx.x * RPB;

    #pragma unroll
    for (int r = 0; r < RPB; ++r)
        in_lds[r][c] = inp[(size_t)(n0 + r) * IN_FEAT + c];
    __syncthreads();

    float accs[RPB] = {0.f, 0.f, 0.f, 0.f};
    float accp[RPB] = {0.f, 0.f, 0.f, 0.f};
    const float* pwrow = PW + (size_t)c * IN_FEAT;

    for (int k = 0; k < IN_FEAT; k += 4) {
        const float w0 = W[(k + 0) * HF + c];
        const float w1 = W[(k + 1) * HF + c];
        const float w2 = W[(k + 2) * HF + c];
        const float w3 = W[(k + 3) * HF + c];
        const float4 pw = *(const float4*)(pwrow + k);
        #pragma unroll
        for (int r = 0; r < RPB; ++r) {
            const float4 xv = *(const float4*)&in_lds[r][k];
            accs[r] = fmaf(xv.x, w0, accs[r]);
            accs[r] = fmaf(xv.y, w1, accs[r]);
            accs[r] = fmaf(xv.z, w2, accs[r]);
            accs[r] = fmaf(xv.w, w3, accs[r]);
            accp[r] = fmaf(xv.x, pw.x, accp[r]);
            accp[r] = fmaf(xv.y, pw.y, accp[r]);
            accp[r] = fmaf(xv.z, pw.z, accp[r]);
            accp[r] = fmaf(xv.w, pw.w, accp[r]);
        }
    }

    const int h = c >> 6, o = c & 63, lane = c & 63;
    const float uv = U[c], vv = V[c];
    const float bb = Bias[c] + PB[c];

    #pragma unroll
    for (int r = 0; r < RPB; ++r) {
        const int n = n0 + r;
        const float sv = accs[r];
        supp[((size_t)h * N_NODES + n) * OUT_F + o] = f2bf(sv);
        float s1 = sv * uv, s2 = sv * vv;
        #pragma unroll
        for (int mm = 32; mm > 0; mm >>= 1) {
            s1 += __shfl_xor(s1, mm);
            s2 += __shfl_xor(s2, mm);
        }
        if (lane == 0) {
            f1[h * N_NODES + n] = s1;
            f2[h * N_NODES + n] = s2;
        }
        outp[(size_t)n * HF + c] = accp[r] + bb;
    }
}

// ---------------------------------------------------------------------------
// K2: per-head global max of f1 (upper bound for softmax shift; leaky is
//     monotone so leaky(max f1 + f2_i) >= max over edges of leaky(f1_j+f2_i))
// ---------------------------------------------------------------------------
__global__ __launch_bounds__(256) void k_f1max(const float* __restrict__ f1,
                                               float* __restrict__ f1max) {
    __shared__ float red[256];
    const int h = blockIdx.x;
    float m = -1e30f;
    for (int j = threadIdx.x; j < N_NODES; j += 256)
        m = fmaxf(m, f1[h * N_NODES + j]);
    red[threadIdx.x] = m;
    __syncthreads();
    for (int s = 128; s > 0; s >>= 1) {
        if (threadIdx.x < s) red[threadIdx.x] = fmaxf(red[threadIdx.x], red[threadIdx.x + s]);
        __syncthreads();
    }
    if (threadIdx.x == 0) f1max[h] = red[0];
}

// ---------------------------------------------------------------------------
// K3: one block per row i; wave h = head h; lanes = output features.
//     adj row staged once in LDS (as u16 nonzero flags) for all 4 heads.
//     Adds the attention result onto the proj already sitting in d_out.
// ---------------------------------------------------------------------------
__global__ __launch_bounds__(256) void k_attn(
    const float* __restrict__ adj,   // [N, N] fp32
    const u16* __restrict__ supp,    // [H][N][64] bf16
    const float* __restrict__ f1,    // [H][N]
    const float* __restrict__ f2,    // [H][N]
    const float* __restrict__ f1max, // [H]
    float* __restrict__ out)         // [N][256] fp32: proj in, proj+attn out
{
    __shared__ __align__(16) u16 arow[N_NODES];   // 16 KiB nonzero flags
    const int i   = blockIdx.x;
    const int tid = threadIdx.x;

    // stage adjacency-row flags with float4 loads
    {
        const float4* src = (const float4*)(adj + (size_t)i * N_NODES);
        #pragma unroll
        for (int t = 0; t < 8; ++t) {
            const int f4 = tid + 256 * t;
            const float4 v = src[f4];
            ushort4 m;
            m.x = (v.x != 0.f); m.y = (v.y != 0.f);
            m.z = (v.z != 0.f); m.w = (v.w != 0.f);
            *(ushort4*)(arow + 4 * f4) = m;
        }
    }
    __syncthreads();

    const int h = tid >> 6, lane = tid & 63;
    const float* f1h = f1 + (size_t)h * N_NODES;
    const float f2i = f2[(size_t)h * N_NODES + i];
    const float m   = leaky(f1max[h] + f2i);   // >= max over edges (monotone)
    const u16* srow = supp + (size_t)h * N_NODES * OUT_F + lane;

    float acc = 0.f, lsum = 0.f;
    for (int jb = 0; jb < N_NODES; jb += 64) {
        const u16 av = arow[jb + lane];
        const float w = leaky(f1h[jb + lane] + f2i);
        const float e = (av != 0) ? __expf(w - m) : 0.f;
        lsum += e;
        unsigned long long ball = __ballot(av != 0);
        while (ball) {
            const int jj = __ffsll((long long)ball) - 1;
            ball &= ball - 1;
            const float ej = __shfl(e, jj);
            const float sv = bf2f(srow[(size_t)(jb + jj) * OUT_F]);
            acc = fmaf(ej, sv, acc);
        }
    }
    #pragma unroll
    for (int mm = 32; mm > 0; mm >>= 1) lsum += __shfl_xor(lsum, mm);

    out[(size_t)i * HF + tid] += acc / lsum;
}

// ---------------------------------------------------------------------------
extern "C" void kernel_launch(void* const* d_in, const int* in_sizes, int n_in,
                              void* d_out, int out_size, void* d_ws, size_t ws_size,
                              hipStream_t stream) {
    const float* inp  = (const float*)d_in[0];  // [8192,256]
    const float* adj  = (const float*)d_in[1];  // [8192,8192]
    const float* W    = (const float*)d_in[2];  // [256,256]
    const float* U    = (const float*)d_in[3];  // [4,64,1]
    const float* V    = (const float*)d_in[4];  // [4,64,1]
    const float* Bias = (const float*)d_in[5];  // [1,256]
    const float* PW   = (const float*)d_in[6];  // [256,256]
    const float* PB   = (const float*)d_in[7];  // [256]
    float* out = (float*)d_out;                 // [8192,256] fp32

    char* ws = (char*)d_ws;
    u16*   supp  = (u16*)(ws);                                   // 4 MiB
    float* f1    = (float*)(ws + (4u << 20));                    // 128 KiB
    float* f2    = (float*)(ws + (4u << 20) + (128u << 10));     // 128 KiB
    float* f1mx  = (float*)(ws + (4u << 20) + (256u << 10));     // 16 B
    // total ws use: ~4.26 MiB

    k_gemm<<<N_NODES / RPB, 256, 0, stream>>>(inp, W, U, V, Bias, PW, PB,
                                              supp, f1, f2, out);
    k_f1max<<<NHEAD, 256, 0, stream>>>(f1, f1mx);
    k_attn<<<N_NODES, 256, 0, stream>>>(adj, supp, f1, f2, f1mx, out);
}

// Round 3
// 616.404 us; speedup vs baseline: 1.5674x; 1.5674x over previous
//
#include <hip/hip_runtime.h>
#include <hip/hip_bf16.h>

#define N_NODES 8192
#define IN_FEAT 256
#define OUT_F   64
#define NHEAD   4
#define HF      256     // NHEAD*OUT_F
#define NEG     0.2f

typedef unsigned short u16;
typedef __attribute__((ext_vector_type(8))) short short8;   // 8 bf16 (4 VGPRs)
typedef __attribute__((ext_vector_type(4))) float f32x4;    // MFMA C/D

__device__ __forceinline__ float bf2f(u16 x) {
    union { unsigned int u; float f; } v; v.u = ((unsigned int)x) << 16; return v.f;
}
__device__ __forceinline__ u16 f2bf(float f) {
    union { unsigned int u; float f; } v; v.f = f;
    unsigned int r = v.u + 0x7FFFu + ((v.u >> 16) & 1u);  // RNE
    return (u16)(r >> 16);
}
__device__ __forceinline__ float leaky(float x) {
    return fmaxf(x, 0.f) + NEG * fminf(x, 0.f);
}

// ---------------------------------------------------------------------------
// K1: per 8 rows: support = X@W (bf16 to ws), f1/f2 head dots,
//     proj = X@Pw^T + proj_b + bias  -> written straight into d_out (fp32).
// ---------------------------------------------------------------------------
#define RPB 8
__global__ __launch_bounds__(256) void k_gemm(
    const float* __restrict__ inp,   // [N, 256]
    const float* __restrict__ W,     // [256, 256] (k-major rows)
    const float* __restrict__ U,     // [H*64] flat
    const float* __restrict__ V,     // [H*64] flat
    const float* __restrict__ Bias,  // [256]
    const float* __restrict__ PW,    // [256 out][256 in]
    const float* __restrict__ PB,    // [256]
    u16*   __restrict__ supp,        // [H][N][64] bf16
    float* __restrict__ f1,          // [H][N]
    float* __restrict__ f2,          // [H][N]
    float* __restrict__ outp)        // [N][256]  proj + bias + proj_b
{
    __shared__ __align__(16) float in_lds[RPB][IN_FEAT];
    const int c  = threadIdx.x;            // output column 0..255
    const int n0 = blockIdx.x * RPB;

    #pragma unroll
    for (int r = 0; r < RPB; ++r)
        in_lds[r][c] = inp[(size_t)(n0 + r) * IN_FEAT + c];
    __syncthreads();

    float accs[RPB], accp[RPB];
    #pragma unroll
    for (int r = 0; r < RPB; ++r) { accs[r] = 0.f; accp[r] = 0.f; }
    const float* pwrow = PW + (size_t)c * IN_FEAT;

    for (int k = 0; k < IN_FEAT; k += 4) {
        const float w0 = W[(k + 0) * HF + c];
        const float w1 = W[(k + 1) * HF + c];
        const float w2 = W[(k + 2) * HF + c];
        const float w3 = W[(k + 3) * HF + c];
        const float4 pw = *(const float4*)(pwrow + k);
        #pragma unroll
        for (int r = 0; r < RPB; ++r) {
            const float4 xv = *(const float4*)&in_lds[r][k];
            accs[r] = fmaf(xv.x, w0, accs[r]);
            accs[r] = fmaf(xv.y, w1, accs[r]);
            accs[r] = fmaf(xv.z, w2, accs[r]);
            accs[r] = fmaf(xv.w, w3, accs[r]);
            accp[r] = fmaf(xv.x, pw.x, accp[r]);
            accp[r] = fmaf(xv.y, pw.y, accp[r]);
            accp[r] = fmaf(xv.z, pw.z, accp[r]);
            accp[r] = fmaf(xv.w, pw.w, accp[r]);
        }
    }

    const int h = c >> 6, o = c & 63, lane = c & 63;
    const float uv = U[c], vv = V[c];
    const float bb = Bias[c] + PB[c];

    #pragma unroll
    for (int r = 0; r < RPB; ++r) {
        const int n = n0 + r;
        const float sv = accs[r];
        supp[((size_t)h * N_NODES + n) * OUT_F + o] = f2bf(sv);
        float s1 = sv * uv, s2 = sv * vv;
        #pragma unroll
        for (int mm = 32; mm > 0; mm >>= 1) {
            s1 += __shfl_xor(s1, mm);
            s2 += __shfl_xor(s2, mm);
        }
        if (lane == 0) {
            f1[h * N_NODES + n] = s1;
            f2[h * N_NODES + n] = s2;
        }
        outp[(size_t)n * HF + c] = accp[r] + bb;
    }
}

// ---------------------------------------------------------------------------
// K2: per-head global max of f1 (upper bound for softmax shift; leaky is
//     monotone so leaky(max f1 + f2_i) >= max over edges of leaky(f1_j+f2_i))
// ---------------------------------------------------------------------------
__global__ __launch_bounds__(256) void k_f1max(const float* __restrict__ f1,
                                               float* __restrict__ f1max) {
    __shared__ float red[256];
    const int h = blockIdx.x;
    float m = -1e30f;
    for (int j = threadIdx.x; j < N_NODES; j += 256)
        m = fmaxf(m, f1[h * N_NODES + j]);
    red[threadIdx.x] = m;
    __syncthreads();
    for (int s = 128; s > 0; s >>= 1) {
        if (threadIdx.x < s) red[threadIdx.x] = fmaxf(red[threadIdx.x], red[threadIdx.x + s]);
        __syncthreads();
    }
    if (threadIdx.x == 0) f1max[h] = red[0];
}

// ---------------------------------------------------------------------------
// K3: MFMA attention. One block per 16-row i-tile; wave w = head w.
//   Phase 1: bit-pack 16 adjacency rows into LDS nibble flags (shared by heads).
//   Phase 2: flash-style j-loop, K=32 per step:
//     e-tile built in registers directly in MFMA A-layout (A[m=lane&15][k=quad*8+jj]),
//     B = supp[h][j, feat] in B-layout (n=lane&15, k=quad*8+jj),
//     4 n-tiles of 16 feats -> 4 mfma_f32_16x16x32_bf16 per step.
//   C layout (verified): col=lane&15, row=quad*4+reg.
// ---------------------------------------------------------------------------
#define TI 16
__global__ __launch_bounds__(256) void k_attn_mfma(
    const float* __restrict__ adj,   // [N, N] fp32
    const u16* __restrict__ supp,    // [H][N][64] bf16
    const float* __restrict__ f1,    // [H][N]
    const float* __restrict__ f2,    // [H][N]
    const float* __restrict__ f1max, // [H]
    float* __restrict__ out)         // [N][256] fp32: proj in, proj+attn out
{
    // nibble flags: byte b of row i holds j=4b..4b+3 at bits 0..3.
    // row stride 1026 u16 (2052 B = 513 words) -> consumer lanes i hit distinct banks.
    __shared__ u16 abits[TI][1026];   // ~32.8 KB

    const int i0   = blockIdx.x * TI;
    const int tid  = threadIdx.x;
    const int wv   = tid >> 6;        // wave = head
    const int lane = tid & 63;
    const int col  = lane & 15;       // m (A) / n (B) / col (C)
    const int quad = lane >> 4;

    // ---- Phase 1: stage adjacency flags (wave wv does rows 4wv..4wv+3) ----
    #pragma unroll
    for (int rr = 0; rr < 4; ++rr) {
        const int r = (wv << 2) + rr;
        const float* ar = adj + (size_t)(i0 + r) * N_NODES;
        #pragma unroll 2
        for (int it = 0; it < 16; ++it) {
            const int j = it * 512 + lane * 8;
            const float4 a0 = *(const float4*)(ar + j);
            const float4 a1 = *(const float4*)(ar + j + 4);
            const unsigned v =
                (unsigned)(a0.x != 0.f)        | ((unsigned)(a0.y != 0.f) << 1) |
                ((unsigned)(a0.z != 0.f) << 2) | ((unsigned)(a0.w != 0.f) << 3) |
                ((unsigned)(a1.x != 0.f) << 8) | ((unsigned)(a1.y != 0.f) << 9) |
                ((unsigned)(a1.z != 0.f) << 10)| ((unsigned)(a1.w != 0.f) << 11);
            abits[r][it * 64 + lane] = (u16)v;
        }
    }
    __syncthreads();

    // ---- Phase 2: flash j-loop ----
    const int h = wv;
    const float* f1h = f1 + (size_t)h * N_NODES;
    const float f2i  = f2[(size_t)h * N_NODES + i0 + col];      // i = col
    const float mi   = leaky(f1max[h] + f2i);                   // >= row max
    const u16* sh    = supp + (size_t)h * N_NODES * OUT_F;

    f32x4 acc[4];
    #pragma unroll
    for (int t = 0; t < 4; ++t) acc[t] = (f32x4){0.f, 0.f, 0.f, 0.f};
    float lsum = 0.f;

    for (int jb = 0; jb < N_NODES; jb += 32) {
        const int jq = jb + (quad << 3);                        // this lane's j base
        const float4 fa = *(const float4*)(f1h + jq);
        const float4 fb = *(const float4*)(f1h + jq + 4);
        const u16 bw = abits[col][(jb >> 3) + quad];            // 8 flag bits

        float fj[8] = {fa.x, fa.y, fa.z, fa.w, fb.x, fb.y, fb.z, fb.w};
        union { short8 v; u16 s[8]; } af;
        #pragma unroll
        for (int jj = 0; jj < 8; ++jj) {
            const float t0 = fj[jj] + f2i;
            const float lw = fmaxf(t0, 0.f) + NEG * fminf(t0, 0.f);
            const int sh_jj = (jj & 3) + ((jj >> 2) << 3);
            const float e = ((bw >> sh_jj) & 1) ? __expf(lw - mi) : 0.f;
            lsum += e;
            af.s[jj] = f2bf(e);
        }

        const u16* bp0 = sh + ((size_t)jq) * OUT_F + col;
        #pragma unroll
        for (int t = 0; t < 4; ++t) {
            union { short8 v; u16 s[8]; } bf;
            const u16* bp = bp0 + (t << 4);
            #pragma unroll
            for (int jj = 0; jj < 8; ++jj) bf.s[jj] = bp[jj * OUT_F];
            acc[t] = __builtin_amdgcn_mfma_f32_16x16x32_bf16(af.v, bf.v, acc[t], 0, 0, 0);
        }
    }

    // denominator: reduce over quads (each quad summed its own k-slice)
    lsum += __shfl_xor(lsum, 16);
    lsum += __shfl_xor(lsum, 32);   // now lane L holds lsum for i = L&15

    // ---- epilogue: divide + add onto proj in d_out ----
    #pragma unroll
    for (int reg = 0; reg < 4; ++reg) {
        const int irow = (quad << 2) + reg;                     // C-layout row
        const float inv = 1.f / __shfl(lsum, irow);
        float* op = out + (size_t)(i0 + irow) * HF + (h << 6) + col;
        #pragma unroll
        for (int t = 0; t < 4; ++t) op[t << 4] += acc[t][reg] * inv;
    }
}

// ---------------------------------------------------------------------------
extern "C" void kernel_launch(void* const* d_in, const int* in_sizes, int n_in,
                              void* d_out, int out_size, void* d_ws, size_t ws_size,
                              hipStream_t stream) {
    const float* inp  = (const float*)d_in[0];  // [8192,256]
    const float* adj  = (const float*)d_in[1];  // [8192,8192]
    const float* W    = (const float*)d_in[2];  // [256,256]
    const float* U    = (const float*)d_in[3];  // [4,64,1]
    const float* V    = (const float*)d_in[4];  // [4,64,1]
    const float* Bias = (const float*)d_in[5];  // [1,256]
    const float* PW   = (const float*)d_in[6];  // [256,256]
    const float* PB   = (const float*)d_in[7];  // [256]
    float* out = (float*)d_out;                 // [8192,256] fp32

    char* ws = (char*)d_ws;
    u16*   supp  = (u16*)(ws);                                   // 4 MiB
    float* f1    = (float*)(ws + (4u << 20));                    // 128 KiB
    float* f2    = (float*)(ws + (4u << 20) + (128u << 10));     // 128 KiB
    float* f1mx  = (float*)(ws + (4u << 20) + (256u << 10));     // 16 B

    k_gemm<<<N_NODES / RPB, 256, 0, stream>>>(inp, W, U, V, Bias, PW, PB,
                                              supp, f1, f2, out);
    k_f1max<<<NHEAD, 256, 0, stream>>>(f1, f1mx);
    k_attn_mfma<<<N_NODES / TI, 256, 0, stream>>>(adj, supp, f1, f2, f1mx, out);
}